// Round 1
// baseline (1531.473 us; speedup 1.0000x reference)
//
#include <hip/hip_runtime.h>
#include <math.h>

#define Bd 4
#define Sd 2048
#define Dd 1024
#define Hd 16
#define HDd 64

typedef __attribute__((ext_vector_type(8))) short bf16x8;
typedef __attribute__((ext_vector_type(4))) float f32x4;

__device__ __forceinline__ unsigned short f2bf(float f) {
  unsigned int u = __float_as_uint(f);
  u += 0x7fffu + ((u >> 16) & 1u);
  return (unsigned short)(u >> 16);
}
__device__ __forceinline__ float bf2f(unsigned int us) {
  return __uint_as_float(us << 16);
}

// ---------------- X fp32 -> bf16 ----------------
__global__ void cvt_x_kernel(const float* __restrict__ x, unsigned short* __restrict__ o) {
  int t = blockIdx.x * 256 + threadIdx.x;   // 2,097,152 threads, 4 elems each
  float4 v = ((const float4*)x)[t];
  ushort4 r;
  r.x = f2bf(v.x); r.y = f2bf(v.y); r.z = f2bf(v.z); r.w = f2bf(v.w);
  ((ushort4*)o)[t] = r;
}

// ---------------- W fp32 [k][n] -> bf16 Wt [n][k] ----------------
__global__ void tr_w_kernel(const float* __restrict__ Wq, const float* __restrict__ Wk,
                            const float* __restrict__ Wv, unsigned short* __restrict__ out) {
  const float* W = (blockIdx.y == 0) ? Wq : ((blockIdx.y == 1) ? Wk : Wv);
  unsigned short* o = out + (size_t)blockIdx.y * Dd * Dd;
  int t = blockIdx.x * 256 + threadIdx.x;   // 1M threads
  int k = t & (Dd - 1), n = t >> 10;
  o[(size_t)n * Dd + k] = f2bf(W[(size_t)k * Dd + n]);   // coalesced writes
}

// ---------------- projection GEMM: [8192,1024] x [1024,1024] ----------------
// vmode 0: out[b][h][s][hd] (Q,K)   vmode 1: out[b][h][hd][s] (V transposed)
__global__ __launch_bounds__(256) void proj_kernel(
    const unsigned short* __restrict__ Xbf, const unsigned short* __restrict__ Wt,
    const float* __restrict__ bias, unsigned short* __restrict__ out, int vmode) {
  __shared__ unsigned short As[128 * 40];  // stride 40 ush = 80 B (16B-mult, bank step 20)
  __shared__ unsigned short Bs[128 * 40];
  const int tid = threadIdx.x;
  const int wave = tid >> 6, lane = tid & 63;
  const int quad = lane >> 4, l16 = lane & 15;
  const int m0 = blockIdx.y * 128, n0 = blockIdx.x * 128;
  const int wm = (wave >> 1) * 64, wn = (wave & 1) * 64;

  f32x4 acc[4][4];
#pragma unroll
  for (int i = 0; i < 4; ++i)
#pragma unroll
    for (int j = 0; j < 4; ++j) { f32x4 z = {0.f, 0.f, 0.f, 0.f}; acc[i][j] = z; }

  for (int k0 = 0; k0 < Dd; k0 += 32) {
    __syncthreads();
#pragma unroll
    for (int it = 0; it < 2; ++it) {
      int idx = tid + it * 256;
      int r = idx >> 2, c = (idx & 3) * 8;
      *(uint4*)(&As[r * 40 + c]) = *(const uint4*)(Xbf + (size_t)(m0 + r) * Dd + k0 + c);
      *(uint4*)(&Bs[r * 40 + c]) = *(const uint4*)(Wt + (size_t)(n0 + r) * Dd + k0 + c);
    }
    __syncthreads();
    bf16x8 af[4], wf[4];
#pragma unroll
    for (int i = 0; i < 4; ++i) af[i] = *(const bf16x8*)(&As[(wm + i * 16 + l16) * 40 + quad * 8]);
#pragma unroll
    for (int j = 0; j < 4; ++j) wf[j] = *(const bf16x8*)(&Bs[(wn + j * 16 + l16) * 40 + quad * 8]);
#pragma unroll
    for (int i = 0; i < 4; ++i)
#pragma unroll
      for (int j = 0; j < 4; ++j)
        acc[i][j] = __builtin_amdgcn_mfma_f32_16x16x32_bf16(af[i], wf[j], acc[i][j], 0, 0, 0);
  }

#pragma unroll
  for (int i = 0; i < 4; ++i)
#pragma unroll
    for (int j = 0; j < 4; ++j) {
      int gcol = n0 + wn + j * 16 + l16;           // h*64+hd
      float bvv = bias[gcol];
      int hh = gcol >> 6, hd = gcol & (HDd - 1);
#pragma unroll
      for (int r = 0; r < 4; ++r) {
        int grow = m0 + wm + i * 16 + quad * 4 + r; // b*S+s
        int bb = grow >> 11, s = grow & (Sd - 1);
        size_t off = (vmode == 0)
            ? (((size_t)(bb * Hd + hh) * Sd + s) * HDd + hd)
            : (((size_t)(bb * Hd + hh) * HDd + hd) * Sd + s);
        out[off] = f2bf(acc[i][j][r] + bvv);
      }
    }
}

// ---------------- RoPE in place on Q,K (layout [b][h][s][hd], pairs) ----------------
__global__ void rope_kernel(unsigned short* __restrict__ Qh, unsigned short* __restrict__ Kh) {
  unsigned int* ptr = (unsigned int*)(blockIdx.y ? Kh : Qh);
  int t = blockIdx.x * 256 + threadIdx.x;  // pair index == uint index
  int i = t & 31;
  int s = (t >> 5) & (Sd - 1);
  unsigned int v = ptr[t];
  float x0 = bf2f(v & 0xffffu), x1 = bf2f(v >> 16);
  float invf = powf(10000.0f, -(float)i * (1.0f / 32.0f));
  float ang = (float)s * invf;
  float sn, cs;
  sincosf(ang, &sn, &cs);
  float o0 = x0 * cs - x1 * sn;
  float o1 = x1 * cs + x0 * sn;
  ptr[t] = (unsigned int)f2bf(o0) | ((unsigned int)f2bf(o1) << 16);
}

// ---------------- fused flash attention + raw score output ----------------
// grid (S/128, B*H), 256 threads (4 waves, each owns 32 Q-rows)
__global__ __launch_bounds__(256) void flash_kernel(
    const unsigned short* __restrict__ Qh, const unsigned short* __restrict__ Kh,
    const unsigned short* __restrict__ Vt, float* __restrict__ ctx,
    float* __restrict__ scores) {
  __shared__ unsigned short Qs[128 * 72];    // 144 B rows (16B-mult, bank step 4)
  __shared__ unsigned short KPs[128 * 136];  // K tile, then P tile (272 B rows)
  __shared__ unsigned short Vs[64 * 136];    // V^T tile [hd][key]

  const int tid = threadIdx.x;
  const int wave = tid >> 6, lane = tid & 63;
  const int quad = lane >> 4, l16 = lane & 15;
  const int bh = blockIdx.y;
  const int b = bh >> 4, h = bh & (Hd - 1);
  const int q0 = blockIdx.x * 128;
  const int sm = wave * 32;

  {
    const unsigned short* src = Qh + ((size_t)bh * Sd + q0) * HDd;
#pragma unroll
    for (int it = 0; it < 4; ++it) {
      int idx = tid + it * 256;
      int r = idx >> 3, c = (idx & 7) * 8;
      *(uint4*)(&Qs[r * 72 + c]) = *(const uint4*)(src + r * HDd + c);
    }
  }

  f32x4 O[2][4];
  float mrow[2][4], lrow[2][4];
#pragma unroll
  for (int rt = 0; rt < 2; ++rt) {
#pragma unroll
    for (int nt = 0; nt < 4; ++nt) { f32x4 z = {0.f, 0.f, 0.f, 0.f}; O[rt][nt] = z; }
#pragma unroll
    for (int j = 0; j < 4; ++j) { mrow[rt][j] = -INFINITY; lrow[rt][j] = 0.0f; }
  }

  const float sscale = 0.03125f;  // 1/sqrt(1024)

  for (int kt = 0; kt < Sd; kt += 128) {
    __syncthreads();  // previous iter's PV reads of KPs/Vs finished
    {
      const unsigned short* srcK = Kh + ((size_t)bh * Sd + kt) * HDd;
#pragma unroll
      for (int it = 0; it < 4; ++it) {
        int idx = tid + it * 256;
        int r = idx >> 3, c = (idx & 7) * 8;
        *(uint4*)(&KPs[r * 136 + c]) = *(const uint4*)(srcK + r * HDd + c);
      }
      const unsigned short* srcV = Vt + (size_t)bh * HDd * Sd + kt;
#pragma unroll
      for (int it = 0; it < 4; ++it) {
        int idx = tid + it * 256;
        int rr = idx >> 4, c = (idx & 15) * 8;
        *(uint4*)(&Vs[rr * 136 + c]) = *(const uint4*)(srcV + (size_t)rr * Sd + c);
      }
    }
    __syncthreads();

    // ---- S = Q K^T for this wave's 32-row strip ----
    f32x4 sf[2][8];
#pragma unroll
    for (int rt = 0; rt < 2; ++rt)
#pragma unroll
      for (int ct = 0; ct < 8; ++ct) { f32x4 z = {0.f, 0.f, 0.f, 0.f}; sf[rt][ct] = z; }

    bf16x8 qa0[2], qa1[2];
#pragma unroll
    for (int rt = 0; rt < 2; ++rt) {
      qa0[rt] = *(const bf16x8*)(&Qs[(sm + rt * 16 + l16) * 72 + quad * 8]);
      qa1[rt] = *(const bf16x8*)(&Qs[(sm + rt * 16 + l16) * 72 + 32 + quad * 8]);
    }
#pragma unroll
    for (int ct = 0; ct < 8; ++ct) {
      bf16x8 kb0 = *(const bf16x8*)(&KPs[(ct * 16 + l16) * 136 + quad * 8]);
      bf16x8 kb1 = *(const bf16x8*)(&KPs[(ct * 16 + l16) * 136 + 32 + quad * 8]);
#pragma unroll
      for (int rt = 0; rt < 2; ++rt) {
        sf[rt][ct] = __builtin_amdgcn_mfma_f32_16x16x32_bf16(qa0[rt], kb0, sf[rt][ct], 0, 0, 0);
        sf[rt][ct] = __builtin_amdgcn_mfma_f32_16x16x32_bf16(qa1[rt], kb1, sf[rt][ct], 0, 0, 0);
      }
    }
    __syncthreads();  // all K reads done before KPs is overwritten with P

    float* scp = scores + ((size_t)bh * Sd + (q0 + sm)) * Sd + kt;
#pragma unroll
    for (int rt = 0; rt < 2; ++rt) {
#pragma unroll
      for (int ct = 0; ct < 8; ++ct)
#pragma unroll
        for (int j = 0; j < 4; ++j) sf[rt][ct][j] *= sscale;

      // raw scaled scores -> global (C-layout: col=l16, row=quad*4+j)
#pragma unroll
      for (int j = 0; j < 4; ++j) {
        float* rp = scp + (size_t)(rt * 16 + quad * 4 + j) * Sd;
#pragma unroll
        for (int ct = 0; ct < 8; ++ct) rp[ct * 16 + l16] = sf[rt][ct][j];
      }

      // online softmax per row (replicated across the 16 lanes of each quad)
#pragma unroll
      for (int j = 0; j < 4; ++j) {
        float mx = sf[rt][0][j];
#pragma unroll
        for (int ct = 1; ct < 8; ++ct) mx = fmaxf(mx, sf[rt][ct][j]);
#pragma unroll
        for (int msk = 1; msk <= 8; msk <<= 1) mx = fmaxf(mx, __shfl_xor(mx, msk, 64));
        float mnew = fmaxf(mrow[rt][j], mx);
        float alpha = __expf(mrow[rt][j] - mnew);
        mrow[rt][j] = mnew;
        float rs = 0.0f;
#pragma unroll
        for (int ct = 0; ct < 8; ++ct) {
          float p = __expf(sf[rt][ct][j] - mnew);
          sf[rt][ct][j] = p;
          rs += p;
        }
#pragma unroll
        for (int msk = 1; msk <= 8; msk <<= 1) rs += __shfl_xor(rs, msk, 64);
        lrow[rt][j] = lrow[rt][j] * alpha + rs;
#pragma unroll
        for (int nt = 0; nt < 4; ++nt) O[rt][nt][j] *= alpha;
      }

      // P (bf16) -> LDS for A-operand layout
#pragma unroll
      for (int j = 0; j < 4; ++j) {
        int row = sm + rt * 16 + quad * 4 + j;
#pragma unroll
        for (int ct = 0; ct < 8; ++ct)
          KPs[row * 136 + ct * 16 + l16] = f2bf(sf[rt][ct][j]);
      }
    }
    __syncthreads();

    // ---- O += P V ----
#pragma unroll
    for (int kk = 0; kk < 4; ++kk) {
      bf16x8 pa0 = *(const bf16x8*)(&KPs[(sm + l16) * 136 + kk * 32 + quad * 8]);
      bf16x8 pa1 = *(const bf16x8*)(&KPs[(sm + 16 + l16) * 136 + kk * 32 + quad * 8]);
#pragma unroll
      for (int nt = 0; nt < 4; ++nt) {
        bf16x8 vb = *(const bf16x8*)(&Vs[(nt * 16 + l16) * 136 + kk * 32 + quad * 8]);
        O[0][nt] = __builtin_amdgcn_mfma_f32_16x16x32_bf16(pa0, vb, O[0][nt], 0, 0, 0);
        O[1][nt] = __builtin_amdgcn_mfma_f32_16x16x32_bf16(pa1, vb, O[1][nt], 0, 0, 0);
      }
    }
  }

  // epilogue: ctx[b][s][h*64+hd] = O / l
  float* cp = ctx + ((size_t)b * Sd + q0 + sm) * Dd + h * HDd;
#pragma unroll
  for (int rt = 0; rt < 2; ++rt)
#pragma unroll
    for (int j = 0; j < 4; ++j) {
      float inv = 1.0f / lrow[rt][j];
      float* rp = cp + (size_t)(rt * 16 + quad * 4 + j) * Dd;
#pragma unroll
      for (int nt = 0; nt < 4; ++nt) rp[nt * 16 + l16] = O[rt][nt][j] * inv;
    }
}

extern "C" void kernel_launch(void* const* d_in, const int* in_sizes, int n_in,
                              void* d_out, int out_size, void* d_ws, size_t ws_size,
                              hipStream_t stream) {
  const float* X  = (const float*)d_in[0];
  const float* Wq = (const float*)d_in[1];
  const float* bq = (const float*)d_in[2];
  const float* Wk = (const float*)d_in[3];
  const float* bk = (const float*)d_in[4];
  const float* Wv = (const float*)d_in[5];
  const float* bv = (const float*)d_in[6];

  float* ctx    = (float*)d_out;
  float* scores = ctx + (size_t)Bd * Sd * Dd;

  unsigned short* ws  = (unsigned short*)d_ws;
  unsigned short* Xbf = ws;                                  // 8192*1024
  unsigned short* Wt  = Xbf + (size_t)8192 * 1024;           // 3 * 1024*1024
  unsigned short* Qh  = Wt + (size_t)3 * 1024 * 1024;        // 8M each
  unsigned short* Kh  = Qh + (size_t)Bd * Hd * Sd * HDd;
  unsigned short* Vt  = Kh + (size_t)Bd * Hd * Sd * HDd;

  cvt_x_kernel<<<8192, 256, 0, stream>>>(X, Xbf);
  tr_w_kernel<<<dim3(4096, 3), 256, 0, stream>>>(Wq, Wk, Wv, Wt);
  proj_kernel<<<dim3(8, 64), 256, 0, stream>>>(Xbf, Wt,                       bq, Qh, 0);
  proj_kernel<<<dim3(8, 64), 256, 0, stream>>>(Xbf, Wt + (size_t)1024 * 1024, bk, Kh, 0);
  proj_kernel<<<dim3(8, 64), 256, 0, stream>>>(Xbf, Wt + (size_t)2048 * 1024, bv, Vt, 1);
  rope_kernel<<<dim3(16384, 2), 256, 0, stream>>>(Qh, Kh);
  flash_kernel<<<dim3(16, 64), 256, 0, stream>>>(Qh, Kh, Vt, ctx, scores);
}